// Round 13
// baseline (248.411 us; speedup 1.0000x reference)
//
#include <hip/hip_runtime.h>
#include <hip/hip_bf16.h>

#define D 128
#define EPB 4096   // edges per binning block
#define CAP 6144   // per-bucket capacity in binned buffer (mean 4096, +32 sigma)
#define CAPQ 2048  // per-quarter LDS edge capacity (mean 1024, +32 sigma)

typedef float f32x4 __attribute__((ext_vector_type(4)));
typedef float f32x2 __attribute__((ext_vector_type(2)));
typedef short short8 __attribute__((ext_vector_type(8)));

// ---------------- bf16 helpers ----------------

__device__ __forceinline__ unsigned bf16_rtn_bits(float x) {
    unsigned u = __float_as_uint(x);
    return (u + 0x7fffu + ((u >> 16) & 1u)) >> 16;   // round-to-nearest-even
}

__device__ __forceinline__ f32x2 pkadd(f32x2 a, f32x2 b) {
    f32x2 d;
    asm("v_pk_add_f32 %0, %1, %2" : "=v"(d) : "v"(a), "v"(b));
    return d;
}

// accumulate 8 bf16 (uint4) into 4 packed f32 pairs
__device__ __forceinline__ void addbf8p(f32x2* acc, uint4 v) {
    f32x2 p0 = {__uint_as_float(v.x << 16), __uint_as_float(v.x & 0xffff0000u)};
    f32x2 p1 = {__uint_as_float(v.y << 16), __uint_as_float(v.y & 0xffff0000u)};
    f32x2 p2 = {__uint_as_float(v.z << 16), __uint_as_float(v.z & 0xffff0000u)};
    f32x2 p3 = {__uint_as_float(v.w << 16), __uint_as_float(v.w & 0xffff0000u)};
    acc[0] = pkadd(acc[0], p0);
    acc[1] = pkadd(acc[1], p1);
    acc[2] = pkadd(acc[2], p2);
    acc[3] = pkadd(acc[3], p3);
}

// ---------------- fused prep: W transpose/convert + x->bf16 + gCursor zeroing ----------------

__global__ __launch_bounds__(256) void k_prep(const float* __restrict__ W1a, const float* __restrict__ W1b,
                                              const float* __restrict__ W2a, const float* __restrict__ W2b,
                                              unsigned short* __restrict__ Wt,
                                              const float4* __restrict__ X, uint4* __restrict__ O,
                                              int n8, int* __restrict__ gz, int nzero) {
    if (blockIdx.x < 256) {
        int m = blockIdx.x >> 6;
        int i = (blockIdx.x & 63) * 256 + threadIdx.x;   // 0..16383
        const float* W = (m == 0) ? W1a : (m == 1) ? W1b : (m == 2) ? W2a : W2b;
        int k = i >> 7, n = i & 127;
        Wt[m * 16384 + n * 128 + k] = (unsigned short)bf16_rtn_bits(W[i]);
        return;
    }
    int i = (blockIdx.x - 256) * 256 + threadIdx.x;
    if (i < nzero) gz[i] = 0;
    if (i >= n8) return;
    float4 a = X[2 * i], b = X[2 * i + 1];
    uint4 o;
    o.x = bf16_rtn_bits(a.x) | (bf16_rtn_bits(a.y) << 16);
    o.y = bf16_rtn_bits(a.z) | (bf16_rtn_bits(a.w) << 16);
    o.z = bf16_rtn_bits(b.x) | (bf16_rtn_bits(b.y) << 16);
    o.w = bf16_rtn_bits(b.z) | (bf16_rtn_bits(b.w) << 16);
    O[i] = o;
}

// ---------------- capacity-binned edge bucketing ----------------
// bucket = dst >> 8. binned[b*CAP ...] holds packed (src<<8)|(dst&255).

__global__ __launch_bounds__(256) void k_bin(const int* __restrict__ src,
                                             const int* __restrict__ dst, int E,
                                             int* __restrict__ gCursor,
                                             unsigned* __restrict__ binned) {
    __shared__ int cnt[512];
    __shared__ int offs[512];
    __shared__ int c2[512];
    __shared__ int gOff[512];
    __shared__ int s[256];
    __shared__ unsigned staged[EPB];
    __shared__ unsigned short bo[EPB];
    int t = threadIdx.x;
    cnt[t] = 0; cnt[t + 256] = 0;
    c2[t] = 0; c2[t + 256] = 0;
    __syncthreads();

    unsigned pk[EPB / 256];
    int bk[EPB / 256];
    int e0 = blockIdx.x * EPB;
#pragma unroll
    for (int i = 0; i < EPB / 256; ++i) {
        int e = e0 + i * 256 + t;
        int b = -1; unsigned p = 0;
        if (e < E) {
            int dv = dst[e], sv = src[e];
            b = dv >> 8;
            p = ((unsigned)sv << 8) | (unsigned)(dv & 255);
            atomicAdd(&cnt[b], 1);
        }
        pk[i] = p; bk[i] = b;
    }
    __syncthreads();
    int v0 = cnt[2 * t], v1 = cnt[2 * t + 1];
    int ps = v0 + v1;
    s[t] = ps;
    __syncthreads();
    for (int off = 1; off < 256; off <<= 1) {
        int tv = (t >= off) ? s[t - off] : 0;
        __syncthreads();
        s[t] += tv;
        __syncthreads();
    }
    int ex = s[t] - ps;
    offs[2 * t] = ex;
    offs[2 * t + 1] = ex + v0;
    if (cnt[2 * t])     gOff[2 * t]     = atomicAdd(&gCursor[2 * t], cnt[2 * t]);
    if (cnt[2 * t + 1]) gOff[2 * t + 1] = atomicAdd(&gCursor[2 * t + 1], cnt[2 * t + 1]);
    __syncthreads();
#pragma unroll
    for (int i = 0; i < EPB / 256; ++i) {
        int b = bk[i];
        if (b >= 0) {
            int p = offs[b] + atomicAdd(&c2[b], 1);
            staged[p] = pk[i];
            bo[p] = (unsigned short)b;
        }
    }
    __syncthreads();
    int total = s[255];
    for (int p = t; p < total; p += 256) {
        int b = bo[p];
        binned[(size_t)b * CAP + gOff[b] + (p - offs[b])] = staged[p];
    }
}

// ---------------- Fused CSR-build + layer-1 aggregation ----------------
// Block = (bucket b, quarter qd): builds its 64 nodes' edge lists in LDS,
// writes rowse/colA for layer-2 reuse, then aggregates its 64 nodes with
// indices read from LDS. H output = layer-1 h_bf.

__global__ __launch_bounds__(256) void k_csragg(const unsigned* __restrict__ binned,
                                                const int* __restrict__ bucketCnt,
                                                int* __restrict__ alloc,
                                                const unsigned short* __restrict__ Xb,
                                                int2* __restrict__ rowse,
                                                int* __restrict__ colA,
                                                unsigned short* __restrict__ H,
                                                int Nn) {
    __shared__ int hist[64], loc[64], cur[64], s64[64];
    __shared__ int colL[CAPQ];
    __shared__ int baseSh;
    const int t = threadIdx.x;
    const int b = blockIdx.x >> 2;
    const int qd = blockIdx.x & 3;
    const int n = bucketCnt[b];
    const unsigned* bp = binned + (size_t)b * CAP;

    if (t < 64) { hist[t] = 0; cur[t] = 0; }
    __syncthreads();
    // histogram my quarter's nodes
    for (int i = t; i < n; i += 256) {
        unsigned w = bp[i];
        int dl = (int)(w & 255u);
        if ((dl >> 6) == qd) atomicAdd(&hist[dl & 63], 1);
    }
    __syncthreads();
    if (t < 64) s64[t] = hist[t];
    __syncthreads();
    for (int off = 1; off < 64; off <<= 1) {
        int v = 0;
        if (t < 64 && t >= off) v = s64[t - off];
        __syncthreads();
        if (t < 64) s64[t] += v;
        __syncthreads();
    }
    if (t < 64) loc[t] = s64[t] - hist[t];
    if (t == 63) baseSh = atomicAdd(alloc, s64[63]);
    __syncthreads();
    const int base = baseSh;
    // compact into LDS + mirror to global colA (coalesced-ish runs) for layer 2
    for (int i = t; i < n; i += 256) {
        unsigned w = bp[i];
        int dl = (int)(w & 255u);
        if ((dl >> 6) == qd) {
            int l = dl & 63;
            int p = loc[l] + atomicAdd(&cur[l], 1);
            int sI = (int)(w >> 8);
            colL[p] = sI;
            colA[base + p] = sI;
        }
    }
    if (t < 64) {
        int node = b * 256 + qd * 64 + t;
        if (node < Nn) rowse[node] = make_int2(base + loc[t], base + loc[t] + hist[t]);
    }
    __syncthreads();

    // aggregation: wave wv handles local nodes wv*16 .. wv*16+15
    const int wv = t >> 6, lane = t & 63, qt = lane >> 4, slot = lane & 15;
    const uint4* x4 = (const uint4*)Xb;
    for (int i = 0; i < 16; ++i) {
        int ln = wv * 16 + i;
        int node = b * 256 + qd * 64 + ln;
        if (node >= Nn) break;   // wave-uniform
        size_t rbase = (size_t)node * 16 + slot;
        f32x2 acc[4] = {{0.f, 0.f}, {0.f, 0.f}, {0.f, 0.f}, {0.f, 0.f}};
        f32x2 acc2[4] = {{0.f, 0.f}, {0.f, 0.f}, {0.f, 0.f}, {0.f, 0.f}};
        if (qt == 0) addbf8p(acc, x4[rbase]);          // self term
        int e = loc[ln], end = loc[ln] + hist[ln];
        for (; e + 16 <= end; e += 16) {
            int s0 = colL[e + qt];
            int s1 = colL[e + 4 + qt];
            int s2 = colL[e + 8 + qt];
            int s3 = colL[e + 12 + qt];
            uint4 v0 = x4[(size_t)s0 * 16 + slot];
            uint4 v1 = x4[(size_t)s1 * 16 + slot];
            uint4 v2 = x4[(size_t)s2 * 16 + slot];
            uint4 v3 = x4[(size_t)s3 * 16 + slot];
            addbf8p(acc, v0);
            addbf8p(acc2, v1);
            addbf8p(acc, v2);
            addbf8p(acc2, v3);
        }
        if (e + 8 <= end) {
            int s0 = colL[e + qt];
            int s1 = colL[e + 4 + qt];
            uint4 v0 = x4[(size_t)s0 * 16 + slot];
            uint4 v1 = x4[(size_t)s1 * 16 + slot];
            addbf8p(acc, v0);
            addbf8p(acc2, v1);
            e += 8;
        }
        for (; e < end; e += 4) {
            int idx = e + qt;
            if (idx < end) {
                int s = colL[idx];
                addbf8p(acc, x4[(size_t)s * 16 + slot]);
            }
        }
        float a8[8];
#pragma unroll
        for (int j = 0; j < 4; ++j) {
            f32x2 tt = pkadd(acc[j], acc2[j]);
            a8[2 * j] = tt[0];
            a8[2 * j + 1] = tt[1];
        }
#pragma unroll
        for (int j = 0; j < 8; ++j) {
            a8[j] += __shfl_xor(a8[j], 16);
            a8[j] += __shfl_xor(a8[j], 32);
        }
        if (qt == 0) {
            uint4 o;
            o.x = bf16_rtn_bits(a8[0]) | (bf16_rtn_bits(a8[1]) << 16);
            o.y = bf16_rtn_bits(a8[2]) | (bf16_rtn_bits(a8[3]) << 16);
            o.z = bf16_rtn_bits(a8[4]) | (bf16_rtn_bits(a8[5]) << 16);
            o.w = bf16_rtn_bits(a8[6]) | (bf16_rtn_bits(a8[7]) << 16);
            ((uint4*)H)[rbase] = o;
        }
    }
}

// ---------------- Aggregation for layer 2 (round-8 form) ----------------

__global__ __launch_bounds__(256) void agg_bf16(const unsigned short* __restrict__ X,
                                                const int2* __restrict__ rowse,
                                                const int* __restrict__ colA,
                                                unsigned short* __restrict__ H, int nnodes) {
    int node = blockIdx.x * 4 + (threadIdx.x >> 6);
    if (node >= nnodes) return;
    int lane = threadIdx.x & 63;
    int qt = lane >> 4, slot = lane & 15;
    const uint4* x4 = (const uint4*)X;
    size_t base = (size_t)node * 16 + slot;

    int2 se = rowse[node];
    int e = se.x, end = se.y;

    f32x2 acc[4] = {{0.f, 0.f}, {0.f, 0.f}, {0.f, 0.f}, {0.f, 0.f}};
    f32x2 acc2[4] = {{0.f, 0.f}, {0.f, 0.f}, {0.f, 0.f}, {0.f, 0.f}};
    if (qt == 0) addbf8p(acc, x4[base]);          // self term once

    for (; e + 16 <= end; e += 16) {
        int s0 = colA[e + qt];
        int s1 = colA[e + 4 + qt];
        int s2 = colA[e + 8 + qt];
        int s3 = colA[e + 12 + qt];
        uint4 v0 = x4[(size_t)s0 * 16 + slot];
        uint4 v1 = x4[(size_t)s1 * 16 + slot];
        uint4 v2 = x4[(size_t)s2 * 16 + slot];
        uint4 v3 = x4[(size_t)s3 * 16 + slot];
        addbf8p(acc, v0);
        addbf8p(acc2, v1);
        addbf8p(acc, v2);
        addbf8p(acc2, v3);
    }
    if (e + 8 <= end) {
        int s0 = colA[e + qt];
        int s1 = colA[e + 4 + qt];
        uint4 v0 = x4[(size_t)s0 * 16 + slot];
        uint4 v1 = x4[(size_t)s1 * 16 + slot];
        addbf8p(acc, v0);
        addbf8p(acc2, v1);
        e += 8;
    }
    for (; e < end; e += 4) {
        int idx = e + qt;
        if (idx < end) {
            int s = colA[idx];
            addbf8p(acc, x4[(size_t)s * 16 + slot]);
        }
    }
    float a8[8];
#pragma unroll
    for (int j = 0; j < 4; ++j) {
        f32x2 t = pkadd(acc[j], acc2[j]);
        a8[2 * j] = t[0];
        a8[2 * j + 1] = t[1];
    }
#pragma unroll
    for (int j = 0; j < 8; ++j) {
        a8[j] += __shfl_xor(a8[j], 16);
        a8[j] += __shfl_xor(a8[j], 32);
    }
    if (qt == 0) {
        uint4 o;
        o.x = bf16_rtn_bits(a8[0]) | (bf16_rtn_bits(a8[1]) << 16);
        o.y = bf16_rtn_bits(a8[2]) | (bf16_rtn_bits(a8[3]) << 16);
        o.z = bf16_rtn_bits(a8[4]) | (bf16_rtn_bits(a8[5]) << 16);
        o.w = bf16_rtn_bits(a8[6]) | (bf16_rtn_bits(a8[7]) << 16);
        ((uint4*)H)[base] = o;
    }
}

// ---------------- MFMA fused MLP — persistent + double-buffered tile prefetch ----------------

template <bool OUT_BF16>
__global__ __launch_bounds__(256) void mlp_mfma(const unsigned short* __restrict__ Hb,
                                                const unsigned short* __restrict__ WaT,
                                                const float* __restrict__ ba,
                                                const unsigned short* __restrict__ WbT,
                                                const float* __restrict__ bb,
                                                void* __restrict__ OutP, int nrows) {
    __shared__ unsigned short sh[2][64 * 128];   // 32KB
    const int tid = threadIdx.x;
    const int wv = tid >> 6, l = tid & 63, q = l >> 4, cl = l & 15;
    const int ntiles = (nrows + 63) >> 6;

    short8 B1[2][4], B2[2][4];
    float bva[2], bvb[2];
#pragma unroll
    for (int cf = 0; cf < 2; ++cf) {
        const unsigned short* wa = WaT + (size_t)(wv * 32 + cf * 16 + cl) * 128 + q * 8;
        const unsigned short* wb = WbT + (size_t)(wv * 32 + cf * 16 + cl) * 128 + q * 8;
#pragma unroll
        for (int kk = 0; kk < 4; ++kk) {
            B1[cf][kk] = *(const short8*)(wa + kk * 32);
            B2[cf][kk] = *(const short8*)(wb + kk * 32);
        }
        bva[cf] = ba[wv * 32 + cf * 16 + cl];
        bvb[cf] = bb[wv * 32 + cf * 16 + cl];
    }

    int tile = blockIdx.x;
    if (tile >= ntiles) return;

    {
        const int rows0 = tile * 64;
        const int nvalid = min(64, nrows - rows0);
        const uint4* src = (const uint4*)(Hb + (size_t)rows0 * 128);
#pragma unroll
        for (int it = 0; it < 4; ++it) {
            int idx = it * 256 + tid;
            int row = idx >> 4, s16 = idx & 15;
            uint4 v = {0u, 0u, 0u, 0u};
            if (row < nvalid) v = src[idx];
            int byteoff = (row << 8) + ((s16 << 4) ^ ((row & 7) << 4));
            *(uint4*)((char*)&sh[0][0] + byteoff) = v;
        }
    }
    int cur = 0;
    __syncthreads();

    while (true) {
        const int rows0 = tile * 64;
        const int nvalid = min(64, nrows - rows0);
        const int nexttile = tile + (int)gridDim.x;
        const bool havenext = nexttile < ntiles;

        uint4 r[4];
        if (havenext) {
            const int nr0 = nexttile * 64;
            const int nnv = min(64, nrows - nr0);
            const uint4* src = (const uint4*)(Hb + (size_t)nr0 * 128);
#pragma unroll
            for (int it = 0; it < 4; ++it) {
                int idx = it * 256 + tid;
                int row = idx >> 4;
                uint4 v = {0u, 0u, 0u, 0u};
                if (row < nnv) v = src[idx];
                r[it] = v;
            }
        }

        const char* shc = (const char*)&sh[cur][0];
        f32x4 acc[4][2];
#pragma unroll
        for (int cf = 0; cf < 2; ++cf) {
            f32x4 a = {bva[cf], bva[cf], bva[cf], bva[cf]};
#pragma unroll
            for (int m = 0; m < 4; ++m) acc[m][cf] = a;
        }
#pragma unroll
        for (int kk = 0; kk < 4; ++kk) {
            short8 a[4];
#pragma unroll
            for (int m = 0; m < 4; ++m) {
                int row = m * 16 + cl;
                int byteoff = (row << 8) + ((kk * 64 + q * 16) ^ ((row & 7) << 4));
                a[m] = *(const short8*)(shc + byteoff);
            }
#pragma unroll
            for (int m = 0; m < 4; ++m)
#pragma unroll
                for (int cf = 0; cf < 2; ++cf)
                    acc[m][cf] = __builtin_amdgcn_mfma_f32_16x16x32_bf16(a[m], B1[cf][kk], acc[m][cf], 0, 0, 0);
        }
        __syncthreads();

#pragma unroll
        for (int m = 0; m < 4; ++m)
#pragma unroll
            for (int cf = 0; cf < 2; ++cf)
#pragma unroll
                for (int rr = 0; rr < 4; ++rr) {
                    int row = m * 16 + q * 4 + rr;
                    int col = wv * 32 + cf * 16 + cl;
                    int byteoff = (row << 8) + ((col * 2) ^ ((row & 7) << 4));
                    *(unsigned short*)((char*)&sh[cur][0] + byteoff) =
                        (unsigned short)bf16_rtn_bits(fmaxf(acc[m][cf][rr], 0.f));
                }
        __syncthreads();

#pragma unroll
        for (int cf = 0; cf < 2; ++cf) {
            f32x4 a = {bvb[cf], bvb[cf], bvb[cf], bvb[cf]};
#pragma unroll
            for (int m = 0; m < 4; ++m) acc[m][cf] = a;
        }
#pragma unroll
        for (int kk = 0; kk < 4; ++kk) {
            short8 a[4];
#pragma unroll
            for (int m = 0; m < 4; ++m) {
                int row = m * 16 + cl;
                int byteoff = (row << 8) + ((kk * 64 + q * 16) ^ ((row & 7) << 4));
                a[m] = *(const short8*)(shc + byteoff);
            }
#pragma unroll
            for (int m = 0; m < 4; ++m)
#pragma unroll
                for (int cf = 0; cf < 2; ++cf)
                    acc[m][cf] = __builtin_amdgcn_mfma_f32_16x16x32_bf16(a[m], B2[cf][kk], acc[m][cf], 0, 0, 0);
        }

#pragma unroll
        for (int m = 0; m < 4; ++m)
#pragma unroll
            for (int cf = 0; cf < 2; ++cf)
#pragma unroll
                for (int rr = 0; rr < 4; ++rr) {
                    int row = m * 16 + q * 4 + rr;
                    if (row < nvalid) {
                        float v = fmaxf(acc[m][cf][rr], 0.f);
                        size_t gi = ((size_t)rows0 + row) * 128 + wv * 32 + cf * 16 + cl;
                        if (OUT_BF16)
                            ((unsigned short*)OutP)[gi] = (unsigned short)bf16_rtn_bits(v);
                        else
                            ((float*)OutP)[gi] = v;
                    }
                }

        if (!havenext) break;
#pragma unroll
        for (int it = 0; it < 4; ++it) {
            int idx = it * 256 + tid;
            int row = idx >> 4, s16 = idx & 15;
            int byteoff = (row << 8) + ((s16 << 4) ^ ((row & 7) << 4));
            *(uint4*)((char*)&sh[cur ^ 1][0] + byteoff) = r[it];
        }
        __syncthreads();
        cur ^= 1;
        tile = nexttile;
    }
}

// ---------------- launch ----------------

extern "C" void kernel_launch(void* const* d_in, const int* in_sizes, int n_in,
                              void* d_out, int out_size, void* d_ws, size_t ws_size,
                              hipStream_t stream) {
    const float* x  = (const float*)d_in[0];
    const int*   ei = (const int*)d_in[1];   // [2,E]: src then dst
    const float* W1a = (const float*)d_in[3];
    const float* b1a = (const float*)d_in[4];
    const float* W1b = (const float*)d_in[5];
    const float* b1b = (const float*)d_in[6];
    const float* W2a = (const float*)d_in[7];
    const float* b2a = (const float*)d_in[8];
    const float* W2b = (const float*)d_in[9];
    const float* b2b = (const float*)d_in[10];
    float* out = (float*)d_out;

    const int Nn = in_sizes[0] / D;
    const int E  = in_sizes[1] / 2;
    const int* srcIdx = ei;
    const int* dstIdx = ei + E;
    const int NB = (Nn + 255) >> 8;

    // workspace layout
    char* w = (char*)d_ws;
    size_t off = 0;
    int2* rowse = (int2*)(w + off);    off += (size_t)Nn * 8;
    off = (off + 255) & ~(size_t)255;
    int* gCursor = (int*)(w + off);    off += (size_t)(NB + 1) * 4;   // +1: alloc counter
    int* alloc = gCursor + NB;
    off = (off + 255) & ~(size_t)255;
    int* colA = (int*)(w + off);       off += (size_t)E * 4;
    off = (off + 255) & ~(size_t)255;
    unsigned short* wsp = (unsigned short*)(w + off); off += (size_t)4 * 16384 * 2;  // 128KB
    off = (off + 255) & ~(size_t)255;
    unsigned short* bufA = (unsigned short*)(w + off); off += (size_t)Nn * 128 * 2;  // x_bf / out1_bf
    off = (off + 255) & ~(size_t)255;
    unsigned short* bufB = (unsigned short*)(w + off);                               // h_bf (layer 2)
    unsigned* binned = (unsigned*)bufB;   // aliases bufB (dead before agg2 writes bufB)
    unsigned short* h1 = (unsigned short*)d_out;  // layer-1 h_bf parks in d_out (overwritten by mlp2)

    unsigned short* W1aT = wsp + 0 * 16384;
    unsigned short* W1bT = wsp + 1 * 16384;
    unsigned short* W2aT = wsp + 2 * 16384;
    unsigned short* W2bT = wsp + 3 * 16384;

    const int gBin = (E + EPB - 1) / EPB;
    const int gPrep = 256 + (Nn * 16 + 255) / 256;
    const int ntiles = (Nn + 63) / 64;
    const int gMlp = (ntiles + 2) / 3;   // exactly 3 tiles per persistent block

    // fused prep: weight transpose + x->bf16 + gCursor/alloc zeroing
    k_prep<<<gPrep, 256, 0, stream>>>(W1a, W1b, W2a, W2b, wsp,
                                      (const float4*)x, (uint4*)bufA, Nn * 16, gCursor, NB + 1);

    // edge bucketing
    k_bin<<<gBin, 256, 0, stream>>>(srcIdx, dstIdx, E, gCursor, binned);

    // fused CSR + layer-1 agg: binned -> (rowse, colA) + h1_bf (in d_out)
    k_csragg<<<NB * 4, 256, 0, stream>>>(binned, gCursor, alloc, bufA, rowse, colA, h1, Nn);
    // layer-1 MLP: h1 -> out1_bf (bufA; x dead)
    mlp_mfma<true><<<gMlp, 256, 0, stream>>>(h1, W1aT, b1a, W1bT, b1b, (void*)bufA, Nn);
    // layer-2 agg (classic): out1_bf -> h_bf (bufB; binned dead)
    agg_bf16<<<(Nn + 3) / 4, 256, 0, stream>>>(bufA, rowse, colA, bufB, Nn);
    // layer-2 MLP -> d_out (f32)
    mlp_mfma<false><<<gMlp, 256, 0, stream>>>(bufB, W2aT, b2a, W2bT, b2b, (void*)out, Nn);
}

// Round 14
// 218.093 us; speedup vs baseline: 1.1390x; 1.1390x over previous
//
#include <hip/hip_runtime.h>
#include <hip/hip_bf16.h>

#define D 128
#define EPB 4096   // edges per binning block
#define CAP 6144   // per-bucket capacity in binned buffer (mean 4096, +32 sigma)

typedef float f32x4 __attribute__((ext_vector_type(4)));
typedef float f32x2 __attribute__((ext_vector_type(2)));
typedef short short8 __attribute__((ext_vector_type(8)));

// ---------------- bf16 helpers ----------------

__device__ __forceinline__ unsigned bf16_rtn_bits(float x) {
    unsigned u = __float_as_uint(x);
    return (u + 0x7fffu + ((u >> 16) & 1u)) >> 16;   // round-to-nearest-even
}

__device__ __forceinline__ f32x2 pkadd(f32x2 a, f32x2 b) {
    f32x2 d;
    asm("v_pk_add_f32 %0, %1, %2" : "=v"(d) : "v"(a), "v"(b));
    return d;
}

// accumulate 8 bf16 (uint4) into 4 packed f32 pairs
__device__ __forceinline__ void addbf8p(f32x2* acc, uint4 v) {
    f32x2 p0 = {__uint_as_float(v.x << 16), __uint_as_float(v.x & 0xffff0000u)};
    f32x2 p1 = {__uint_as_float(v.y << 16), __uint_as_float(v.y & 0xffff0000u)};
    f32x2 p2 = {__uint_as_float(v.z << 16), __uint_as_float(v.z & 0xffff0000u)};
    f32x2 p3 = {__uint_as_float(v.w << 16), __uint_as_float(v.w & 0xffff0000u)};
    acc[0] = pkadd(acc[0], p0);
    acc[1] = pkadd(acc[1], p1);
    acc[2] = pkadd(acc[2], p2);
    acc[3] = pkadd(acc[3], p3);
}

// ---------------- fused prep: W transpose/convert + x->bf16 + gCursor zeroing ----------------
// blocks [0,256): weight transpose (64 blocks per matrix)
// blocks [256, ...): x f32 -> bf16, 8 elems/thread; first blocks zero gCursor

__global__ __launch_bounds__(256) void k_prep(const float* __restrict__ W1a, const float* __restrict__ W1b,
                                              const float* __restrict__ W2a, const float* __restrict__ W2b,
                                              unsigned short* __restrict__ Wt,
                                              const float4* __restrict__ X, uint4* __restrict__ O,
                                              int n8, int* __restrict__ gz, int nzero) {
    if (blockIdx.x < 256) {
        int m = blockIdx.x >> 6;
        int i = (blockIdx.x & 63) * 256 + threadIdx.x;   // 0..16383
        const float* W = (m == 0) ? W1a : (m == 1) ? W1b : (m == 2) ? W2a : W2b;
        int k = i >> 7, n = i & 127;
        Wt[m * 16384 + n * 128 + k] = (unsigned short)bf16_rtn_bits(W[i]);
        return;
    }
    int i = (blockIdx.x - 256) * 256 + threadIdx.x;
    if (i < nzero) gz[i] = 0;
    if (i >= n8) return;
    float4 a = X[2 * i], b = X[2 * i + 1];
    uint4 o;
    o.x = bf16_rtn_bits(a.x) | (bf16_rtn_bits(a.y) << 16);
    o.y = bf16_rtn_bits(a.z) | (bf16_rtn_bits(a.w) << 16);
    o.z = bf16_rtn_bits(b.x) | (bf16_rtn_bits(b.y) << 16);
    o.w = bf16_rtn_bits(b.z) | (bf16_rtn_bits(b.w) << 16);
    O[i] = o;
}

// ---------------- capacity-binned CSR build ----------------

__global__ __launch_bounds__(256) void k_bin(const int* __restrict__ src,
                                             const int* __restrict__ dst, int E,
                                             int* __restrict__ gCursor,
                                             unsigned* __restrict__ binned) {
    __shared__ int cnt[512];
    __shared__ int offs[512];
    __shared__ int c2[512];
    __shared__ int gOff[512];
    __shared__ int s[256];
    __shared__ unsigned staged[EPB];
    __shared__ unsigned short bo[EPB];
    int t = threadIdx.x;
    cnt[t] = 0; cnt[t + 256] = 0;
    c2[t] = 0; c2[t + 256] = 0;
    __syncthreads();

    unsigned pk[EPB / 256];
    int bk[EPB / 256];
    int e0 = blockIdx.x * EPB;
#pragma unroll
    for (int i = 0; i < EPB / 256; ++i) {
        int e = e0 + i * 256 + t;
        int b = -1; unsigned p = 0;
        if (e < E) {
            int dv = dst[e], sv = src[e];
            b = dv >> 8;
            p = ((unsigned)sv << 8) | (unsigned)(dv & 255);
            atomicAdd(&cnt[b], 1);
        }
        pk[i] = p; bk[i] = b;
    }
    __syncthreads();
    int v0 = cnt[2 * t], v1 = cnt[2 * t + 1];
    int ps = v0 + v1;
    s[t] = ps;
    __syncthreads();
    for (int off = 1; off < 256; off <<= 1) {
        int tv = (t >= off) ? s[t - off] : 0;
        __syncthreads();
        s[t] += tv;
        __syncthreads();
    }
    int ex = s[t] - ps;
    offs[2 * t] = ex;
    offs[2 * t + 1] = ex + v0;
    if (cnt[2 * t])     gOff[2 * t]     = atomicAdd(&gCursor[2 * t], cnt[2 * t]);
    if (cnt[2 * t + 1]) gOff[2 * t + 1] = atomicAdd(&gCursor[2 * t + 1], cnt[2 * t + 1]);
    __syncthreads();
#pragma unroll
    for (int i = 0; i < EPB / 256; ++i) {
        int b = bk[i];
        if (b >= 0) {
            int p = offs[b] + atomicAdd(&c2[b], 1);
            staged[p] = pk[i];
            bo[p] = (unsigned short)b;
        }
    }
    __syncthreads();
    int total = s[255];
    for (int p = t; p < total; p += 256) {
        int b = bo[p];
        binned[(size_t)b * CAP + gOff[b] + (p - offs[b])] = staged[p];
    }
}

__global__ __launch_bounds__(256) void k_csr(const unsigned* __restrict__ binned,
                                             const int* __restrict__ bucketCnt,
                                             int* __restrict__ alloc,
                                             int2* __restrict__ rowse,
                                             int* __restrict__ colA,
                                             int Nn) {
    __shared__ int hist[256], loc[256], cur[256], s[256];
    __shared__ int baseSh;
    int t = threadIdx.x, b = blockIdx.x;
    int n = bucketCnt[b];
    const unsigned* bp = binned + (size_t)b * CAP;
    hist[t] = 0; cur[t] = 0;
    __syncthreads();
    for (int i = t; i < n; i += 256) atomicAdd(&hist[bp[i] & 255u], 1);
    __syncthreads();
    int v = hist[t];
    s[t] = v;
    __syncthreads();
    for (int off = 1; off < 256; off <<= 1) {
        int tv = (t >= off) ? s[t - off] : 0;
        __syncthreads();
        s[t] += tv;
        __syncthreads();
    }
    loc[t] = s[t] - v;
    if (t == 255) baseSh = atomicAdd(alloc, s[255]);
    __syncthreads();
    int base = baseSh;
    int node = b * 256 + t;
    if (node < Nn) rowse[node] = make_int2(base + loc[t], base + loc[t] + v);
    for (int i = t; i < n; i += 256) {
        unsigned w = bp[i];
        int dl = (int)(w & 255u);
        int p = atomicAdd(&cur[dl], 1);
        colA[base + loc[dl] + p] = (int)(w >> 8);
    }
}

// ---------------- Aggregation (round-8 form: 4 edges/gather, 16-edge unroll) ----------------

__global__ __launch_bounds__(256) void agg_bf16(const unsigned short* __restrict__ X,
                                                const int2* __restrict__ rowse,
                                                const int* __restrict__ colA,
                                                unsigned short* __restrict__ H, int nnodes) {
    int node = blockIdx.x * 4 + (threadIdx.x >> 6);
    if (node >= nnodes) return;
    int lane = threadIdx.x & 63;
    int qt = lane >> 4, slot = lane & 15;
    const uint4* x4 = (const uint4*)X;
    size_t base = (size_t)node * 16 + slot;

    int2 se = rowse[node];
    int e = se.x, end = se.y;

    f32x2 acc[4] = {{0.f, 0.f}, {0.f, 0.f}, {0.f, 0.f}, {0.f, 0.f}};
    f32x2 acc2[4] = {{0.f, 0.f}, {0.f, 0.f}, {0.f, 0.f}, {0.f, 0.f}};
    if (qt == 0) addbf8p(acc, x4[base]);          // self term once

    for (; e + 16 <= end; e += 16) {
        int s0 = colA[e + qt];
        int s1 = colA[e + 4 + qt];
        int s2 = colA[e + 8 + qt];
        int s3 = colA[e + 12 + qt];
        uint4 v0 = x4[(size_t)s0 * 16 + slot];
        uint4 v1 = x4[(size_t)s1 * 16 + slot];
        uint4 v2 = x4[(size_t)s2 * 16 + slot];
        uint4 v3 = x4[(size_t)s3 * 16 + slot];
        addbf8p(acc, v0);
        addbf8p(acc2, v1);
        addbf8p(acc, v2);
        addbf8p(acc2, v3);
    }
    if (e + 8 <= end) {
        int s0 = colA[e + qt];
        int s1 = colA[e + 4 + qt];
        uint4 v0 = x4[(size_t)s0 * 16 + slot];
        uint4 v1 = x4[(size_t)s1 * 16 + slot];
        addbf8p(acc, v0);
        addbf8p(acc2, v1);
        e += 8;
    }
    for (; e < end; e += 4) {
        int idx = e + qt;
        if (idx < end) {
            int s = colA[idx];
            addbf8p(acc, x4[(size_t)s * 16 + slot]);
        }
    }
    float a8[8];
#pragma unroll
    for (int j = 0; j < 4; ++j) {
        f32x2 t = pkadd(acc[j], acc2[j]);
        a8[2 * j] = t[0];
        a8[2 * j + 1] = t[1];
    }
#pragma unroll
    for (int j = 0; j < 8; ++j) {
        a8[j] += __shfl_xor(a8[j], 16);
        a8[j] += __shfl_xor(a8[j], 32);
    }
    if (qt == 0) {
        uint4 o;
        o.x = bf16_rtn_bits(a8[0]) | (bf16_rtn_bits(a8[1]) << 16);
        o.y = bf16_rtn_bits(a8[2]) | (bf16_rtn_bits(a8[3]) << 16);
        o.z = bf16_rtn_bits(a8[4]) | (bf16_rtn_bits(a8[5]) << 16);
        o.w = bf16_rtn_bits(a8[6]) | (bf16_rtn_bits(a8[7]) << 16);
        ((uint4*)H)[base] = o;
    }
}

// ---------------- MFMA fused MLP — persistent + double-buffered tile prefetch ----------------

template <bool OUT_BF16>
__global__ __launch_bounds__(256) void mlp_mfma(const unsigned short* __restrict__ Hb,
                                                const unsigned short* __restrict__ WaT,
                                                const float* __restrict__ ba,
                                                const unsigned short* __restrict__ WbT,
                                                const float* __restrict__ bb,
                                                void* __restrict__ OutP, int nrows) {
    __shared__ unsigned short sh[2][64 * 128];   // 32KB
    const int tid = threadIdx.x;
    const int wv = tid >> 6, l = tid & 63, q = l >> 4, cl = l & 15;
    const int ntiles = (nrows + 63) >> 6;

    short8 B1[2][4], B2[2][4];
    float bva[2], bvb[2];
#pragma unroll
    for (int cf = 0; cf < 2; ++cf) {
        const unsigned short* wa = WaT + (size_t)(wv * 32 + cf * 16 + cl) * 128 + q * 8;
        const unsigned short* wb = WbT + (size_t)(wv * 32 + cf * 16 + cl) * 128 + q * 8;
#pragma unroll
        for (int kk = 0; kk < 4; ++kk) {
            B1[cf][kk] = *(const short8*)(wa + kk * 32);
            B2[cf][kk] = *(const short8*)(wb + kk * 32);
        }
        bva[cf] = ba[wv * 32 + cf * 16 + cl];
        bvb[cf] = bb[wv * 32 + cf * 16 + cl];
    }

    int tile = blockIdx.x;
    if (tile >= ntiles) return;

    {
        const int rows0 = tile * 64;
        const int nvalid = min(64, nrows - rows0);
        const uint4* src = (const uint4*)(Hb + (size_t)rows0 * 128);
#pragma unroll
        for (int it = 0; it < 4; ++it) {
            int idx = it * 256 + tid;
            int row = idx >> 4, s16 = idx & 15;
            uint4 v = {0u, 0u, 0u, 0u};
            if (row < nvalid) v = src[idx];
            int byteoff = (row << 8) + ((s16 << 4) ^ ((row & 7) << 4));
            *(uint4*)((char*)&sh[0][0] + byteoff) = v;
        }
    }
    int cur = 0;
    __syncthreads();

    while (true) {
        const int rows0 = tile * 64;
        const int nvalid = min(64, nrows - rows0);
        const int nexttile = tile + (int)gridDim.x;
        const bool havenext = nexttile < ntiles;

        uint4 r[4];
        if (havenext) {
            const int nr0 = nexttile * 64;
            const int nnv = min(64, nrows - nr0);
            const uint4* src = (const uint4*)(Hb + (size_t)nr0 * 128);
#pragma unroll
            for (int it = 0; it < 4; ++it) {
                int idx = it * 256 + tid;
                int row = idx >> 4;
                uint4 v = {0u, 0u, 0u, 0u};
                if (row < nnv) v = src[idx];
                r[it] = v;
            }
        }

        const char* shc = (const char*)&sh[cur][0];
        f32x4 acc[4][2];
#pragma unroll
        for (int cf = 0; cf < 2; ++cf) {
            f32x4 a = {bva[cf], bva[cf], bva[cf], bva[cf]};
#pragma unroll
            for (int m = 0; m < 4; ++m) acc[m][cf] = a;
        }
#pragma unroll
        for (int kk = 0; kk < 4; ++kk) {
            short8 a[4];
#pragma unroll
            for (int m = 0; m < 4; ++m) {
                int row = m * 16 + cl;
                int byteoff = (row << 8) + ((kk * 64 + q * 16) ^ ((row & 7) << 4));
                a[m] = *(const short8*)(shc + byteoff);
            }
#pragma unroll
            for (int m = 0; m < 4; ++m)
#pragma unroll
                for (int cf = 0; cf < 2; ++cf)
                    acc[m][cf] = __builtin_amdgcn_mfma_f32_16x16x32_bf16(a[m], B1[cf][kk], acc[m][cf], 0, 0, 0);
        }
        __syncthreads();

#pragma unroll
        for (int m = 0; m < 4; ++m)
#pragma unroll
            for (int cf = 0; cf < 2; ++cf)
#pragma unroll
                for (int rr = 0; rr < 4; ++rr) {
                    int row = m * 16 + q * 4 + rr;
                    int col = wv * 32 + cf * 16 + cl;
                    int byteoff = (row << 8) + ((col * 2) ^ ((row & 7) << 4));
                    *(unsigned short*)((char*)&sh[cur][0] + byteoff) =
                        (unsigned short)bf16_rtn_bits(fmaxf(acc[m][cf][rr], 0.f));
                }
        __syncthreads();

#pragma unroll
        for (int cf = 0; cf < 2; ++cf) {
            f32x4 a = {bvb[cf], bvb[cf], bvb[cf], bvb[cf]};
#pragma unroll
            for (int m = 0; m < 4; ++m) acc[m][cf] = a;
        }
#pragma unroll
        for (int kk = 0; kk < 4; ++kk) {
            short8 a[4];
#pragma unroll
            for (int m = 0; m < 4; ++m) {
                int row = m * 16 + cl;
                int byteoff = (row << 8) + ((kk * 64 + q * 16) ^ ((row & 7) << 4));
                a[m] = *(const short8*)(shc + byteoff);
            }
#pragma unroll
            for (int m = 0; m < 4; ++m)
#pragma unroll
                for (int cf = 0; cf < 2; ++cf)
                    acc[m][cf] = __builtin_amdgcn_mfma_f32_16x16x32_bf16(a[m], B2[cf][kk], acc[m][cf], 0, 0, 0);
        }

#pragma unroll
        for (int m = 0; m < 4; ++m)
#pragma unroll
            for (int cf = 0; cf < 2; ++cf)
#pragma unroll
                for (int rr = 0; rr < 4; ++rr) {
                    int row = m * 16 + q * 4 + rr;
                    if (row < nvalid) {
                        float v = fmaxf(acc[m][cf][rr], 0.f);
                        size_t gi = ((size_t)rows0 + row) * 128 + wv * 32 + cf * 16 + cl;
                        if (OUT_BF16)
                            ((unsigned short*)OutP)[gi] = (unsigned short)bf16_rtn_bits(v);
                        else
                            ((float*)OutP)[gi] = v;
                    }
                }

        if (!havenext) break;
#pragma unroll
        for (int it = 0; it < 4; ++it) {
            int idx = it * 256 + tid;
            int row = idx >> 4, s16 = idx & 15;
            int byteoff = (row << 8) + ((s16 << 4) ^ ((row & 7) << 4));
            *(uint4*)((char*)&sh[cur ^ 1][0] + byteoff) = r[it];
        }
        __syncthreads();
        cur ^= 1;
        tile = nexttile;
    }
}

// ---------------- launch ----------------

extern "C" void kernel_launch(void* const* d_in, const int* in_sizes, int n_in,
                              void* d_out, int out_size, void* d_ws, size_t ws_size,
                              hipStream_t stream) {
    const float* x  = (const float*)d_in[0];
    const int*   ei = (const int*)d_in[1];   // [2,E]: src then dst
    const float* W1a = (const float*)d_in[3];
    const float* b1a = (const float*)d_in[4];
    const float* W1b = (const float*)d_in[5];
    const float* b1b = (const float*)d_in[6];
    const float* W2a = (const float*)d_in[7];
    const float* b2a = (const float*)d_in[8];
    const float* W2b = (const float*)d_in[9];
    const float* b2b = (const float*)d_in[10];
    float* out = (float*)d_out;

    const int Nn = in_sizes[0] / D;
    const int E  = in_sizes[1] / 2;
    const int* srcIdx = ei;
    const int* dstIdx = ei + E;
    const int NB = (Nn + 255) >> 8;

    // workspace layout
    char* w = (char*)d_ws;
    size_t off = 0;
    int2* rowse = (int2*)(w + off);    off += (size_t)Nn * 8;
    off = (off + 255) & ~(size_t)255;
    int* gCursor = (int*)(w + off);    off += (size_t)(NB + 1) * 4;   // +1: alloc counter
    int* alloc = gCursor + NB;
    off = (off + 255) & ~(size_t)255;
    int* colA = (int*)(w + off);       off += (size_t)E * 4;
    off = (off + 255) & ~(size_t)255;
    unsigned short* wsp = (unsigned short*)(w + off); off += (size_t)4 * 16384 * 2;  // 128KB
    off = (off + 255) & ~(size_t)255;
    unsigned short* bufA = (unsigned short*)(w + off); off += (size_t)Nn * 128 * 2;  // x_bf / out1_bf
    off = (off + 255) & ~(size_t)255;
    unsigned short* bufB = (unsigned short*)(w + off);                               // h_bf
    unsigned* binned = (unsigned*)bufB;   // aliases bufB (9.6MB <= 25.6MB; dead before agg1 writes)

    unsigned short* W1aT = wsp + 0 * 16384;
    unsigned short* W1bT = wsp + 1 * 16384;
    unsigned short* W2aT = wsp + 2 * 16384;
    unsigned short* W2bT = wsp + 3 * 16384;

    const int gBin = (E + EPB - 1) / EPB;
    const int gPrep = 256 + (Nn * 16 + 255) / 256;

    // fused prep: weight transpose + x->bf16 + gCursor zeroing
    k_prep<<<gPrep, 256, 0, stream>>>(W1a, W1b, W2a, W2b, wsp,
                                      (const float4*)x, (uint4*)bufA, Nn * 16, gCursor, NB + 1);

    // CSR build (capacity-binned)
    k_bin<<<gBin, 256, 0, stream>>>(srcIdx, dstIdx, E, gCursor, binned);
    k_csr<<<NB, 256, 0, stream>>>(binned, gCursor, alloc, rowse, colA, Nn);

    const int gAgg = (Nn + 3) / 4;
    const int gMlp = 512;   // persistent blocks, grid-stride over tiles

    // Layer 1: agg(x_bf) -> h_bf; mlp -> out1_bf (bufA; x dead)
    agg_bf16<<<gAgg, 256, 0, stream>>>(bufA, rowse, colA, bufB, Nn);
    mlp_mfma<true><<<gMlp, 256, 0, stream>>>(bufB, W1aT, b1a, W1bT, b1b, (void*)bufA, Nn);
    // Layer 2: agg(out1_bf) -> h_bf; mlp -> d_out (f32)
    agg_bf16<<<gAgg, 256, 0, stream>>>(bufA, rowse, colA, bufB, Nn);
    mlp_mfma<false><<<gMlp, 256, 0, stream>>>(bufB, W2aT, b2a, W2bT, b2b, (void*)out, Nn);
}